// Round 11
// baseline (306.301 us; speedup 1.0000x reference)
//
#include <hip/hip_runtime.h>
#include <math.h>

// Retinex MSR via GEMM: blur_s = G_s * X * G_s  (G_s symmetric Toeplitz blur).
// xconv: X -> f16. gemm1 (z=144): Ys^T[a][b] = sum_k G_s[a][k] X[b][k].
// gemm2 (z=48):  out = sum_s log(G_s*Y_s + 1)/3, fused min/max reduction.
// NEW: A-panel (G rows, 128x512 f16 = 128KB) resident in LDS per block,
// staged once (pre-swizzled source -> conflict-free reads). K-loop stages ONLY
// B (8KB/step for 128x128x32 MACs = 131 FLOP/B -> L2-feed cap ~52% MfmaUtil).
// 8 waves, wave-tile 64x32, 3 B-buffers, counted vmcnt(1) + raw s_barrier.

#define NSL 48

// d_ws layout:
#define W0_OFF 0      // sigma 15:  16 zero | 91 w | zeros   (alloc 512 floats)
#define W1_OFF 512    // sigma 80:  16 zero | 481 w | zeros  (alloc 768)
#define W2_OFF 1280   // sigma 250: 16 zero | 1501 w | zeros (alloc 1536)
#define MM_OFF 2816   // 6 uints: min[3], max[3]
#define G16_BYTE_OFF 16384     // 3 * 512*512 f16   (1.5 MiB)
#define X16_BYTE_OFF 1589248   // 48 * 512*512 f16  (24 MiB)
#define T16_BYTE_OFF 26755072  // 3 * 48 * 512*512 f16 (72 MiB)

typedef _Float16 half8 __attribute__((ext_vector_type(8)));
typedef float f32x4 __attribute__((ext_vector_type(4)));

__device__ __forceinline__ void gload16(const void* g, void* l) {
  __builtin_amdgcn_global_load_lds(
      (const __attribute__((address_space(1))) void*)g,
      (__attribute__((address_space(3))) void*)l, 16, 0, 0);
}

#define WAITV1() asm volatile("s_waitcnt vmcnt(1)" ::: "memory")
#define WAITV0() asm volatile("s_waitcnt vmcnt(0)" ::: "memory")
#define SCHEDB() __builtin_amdgcn_sched_barrier(0)
#define BARRIER() __builtin_amdgcn_s_barrier()

// ---------------- weights ----------------
__global__ void wkern(float* __restrict__ ws) {
  __shared__ float red[256];
  const int s = blockIdx.x;
  const int Ks[3] = {91, 481, 1501};
  const float sg[3] = {15.f, 80.f, 250.f};
  const int off[3] = {W0_OFF, W1_OFF, W2_OFF};
  const int alloc[3] = {512, 768, 1536};
  const int K = Ks[s], A = alloc[s];
  float* wb = ws + off[s];
  const int t = threadIdx.x;
  for (int i = t; i < A; i += 256) wb[i] = 0.f;
  __syncthreads();
  const float inv2s2 = 1.f / (2.f * sg[s] * sg[s]);
  float part = 0.f;
  for (int i = t; i < K; i += 256) {
    const float d = (float)(i - K / 2);
    const float e = __expf(-d * d * inv2s2);
    wb[16 + i] = e;
    part += e;
  }
  red[t] = part;
  __syncthreads();
  for (int st = 128; st > 0; st >>= 1) {
    if (t < st) red[t] += red[t + st];
    __syncthreads();
  }
  const float inv = 1.f / red[0];
  for (int i = t; i < K; i += 256) wb[16 + i] *= inv;
}

__global__ void mm_init(unsigned* __restrict__ mm) {
  const int t = threadIdx.x;
  if (t < 3) mm[t] = 0xFFFFFFFFu;
  else if (t < 6) mm[t] = 0u;
}

// ---------------- build G matrices (fp16) ----------------
__global__ void gkern(const float* __restrict__ ws, _Float16* __restrict__ gb) {
  const int y = blockIdx.x;
  const int s = blockIdx.y;
  const int Rs[3] = {45, 240, 750};
  const int off[3] = {W0_OFF, W1_OFF, W2_OFF};
  const float* w = ws + off[s] + 16;
  _Float16* g = gb + ((size_t)s << 18) + ((size_t)y << 9);
  const int R = Rs[s], K = 2 * R + 1;
  for (int x = threadIdx.x; x < 512; x += 256) {
    const int i = x - y + R;
    const float v = (i >= 0 && i < K) ? w[i] : 0.f;
    g[x] = (_Float16)v;
  }
}

// ---------------- X fp32 -> fp16 ----------------
__global__ __launch_bounds__(256) void xconv(const float* __restrict__ X,
                                             _Float16* __restrict__ X16) {
  const size_t i = ((size_t)blockIdx.x * 256 + threadIdx.x) << 3;
  const float4 v0 = *reinterpret_cast<const float4*>(X + i);
  const float4 v1 = *reinterpret_cast<const float4*>(X + i + 4);
  half8 h;
  h[0] = (_Float16)v0.x; h[1] = (_Float16)v0.y;
  h[2] = (_Float16)v0.z; h[3] = (_Float16)v0.w;
  h[4] = (_Float16)v1.x; h[5] = (_Float16)v1.y;
  h[6] = (_Float16)v1.z; h[7] = (_Float16)v1.w;
  *reinterpret_cast<half8*>(X16 + i) = h;
}

// A preload: 128 rows x 512 cols f16, LDS granule (row, gl) holds source
// granule gl ^ (row&7)  (granule = 8 elems = 16B). 16 gloads/thread, 512 thr.
#define PRELOAD_A()                                                 \
  do {                                                              \
    _Pragma("unroll") for (int i = 0; i < 16; ++i) {                \
      const int c = (i << 9) + t;                                   \
      const int row = c >> 6;                                       \
      const int kc = c & 63;                                        \
      gload16(Ap + ((size_t)(bm + row) << 9) +                      \
                  ((kc ^ (row & 7)) << 3),                          \
              &As[c << 3]);                                         \
    }                                                               \
  } while (0)

// B stage: one 128x32 tile, 1 gload/thread; LDS granule (n, kc) holds source
// granule kc ^ (n&3). pB advances 32 elems per stage.
#define STAGE_B(buf)                       \
  do {                                     \
    gload16(pB, &Bs[buf][t << 3]);         \
    pB += 32;                              \
  } while (0)

// Fragments + MFMA: wave-tile 64x32 (wm 2x64, wn 4x32), acc[4][2].
#define FRAGS_AND_MFMA(buf, kt_)                                                    \
  do {                                                                              \
    half8 af[4], bf[2];                                                             \
    _Pragma("unroll") for (int f = 0; f < 4; ++f) {                                 \
      const int row = wm + (f << 4) + lr;                                           \
      const int g = ((kt_) << 2) + lg;                                              \
      af[f] = *reinterpret_cast<const half8*>(                                      \
          &As[(row << 9) + ((g ^ (row & 7)) << 3)]);                                \
    }                                                                               \
    _Pragma("unroll") for (int f = 0; f < 2; ++f) {                                 \
      const int n = wn + (f << 4) + lr;                                             \
      bf[f] = *reinterpret_cast<const half8*>(                                      \
          &Bs[buf][(n << 5) + ((lg ^ (n & 3)) << 3)]);                              \
    }                                                                               \
    _Pragma("unroll") for (int fm = 0; fm < 4; ++fm)                                \
        _Pragma("unroll") for (int fn = 0; fn < 2; ++fn)                            \
        acc[fm][fn] = __builtin_amdgcn_mfma_f32_16x16x32_f16(af[fm], bf[fn],        \
                                                             acc[fm][fn], 0, 0, 0); \
  } while (0)

// K-loop: A resident; B 3-buffer mod-3, counted vmcnt(1), one barrier/step.
// Safety: identical to the round-8-verified pipeline (per-wave vmcnt before the
// shared barrier; buf (cb+2)%3 was consumed >=1 barrier ago).
#define K_PIPELINE_LOOP()                                                           \
  do {                                                                              \
    PRELOAD_A();                                                                    \
    const int nrow_ = t >> 2;                                                       \
    const int kc4_ = t & 3;                                                         \
    const _Float16* pB = Bp + ((size_t)(bn + nrow_) << 9) + (klo << 5) +            \
                         ((kc4_ ^ (nrow_ & 3)) << 3);                               \
    STAGE_B(0);                                                                     \
    STAGE_B(1);                                                                     \
    int cb = 0;                                                                     \
    for (int kt = klo; kt <= khi; ++kt) {                                           \
      if (kt < khi) { WAITV1(); } else { WAITV0(); }                                \
      SCHEDB();                                                                     \
      BARRIER();                                                                    \
      SCHEDB();                                                                     \
      if (kt + 2 <= khi) {                                                          \
        const int sb = (cb + 2 >= 3) ? cb - 1 : cb + 2;                             \
        STAGE_B(sb);                                                                \
      }                                                                             \
      FRAGS_AND_MFMA(cb, kt);                                                       \
      cb = (cb == 2) ? 0 : cb + 1;                                                  \
    }                                                                               \
  } while (0)

// ---------------- stage 1: Ys^T = G_s * X^T (B = X rows), one dispatch all s ----------------
__global__ __launch_bounds__(512, 2) void gemm1_k(const _Float16* __restrict__ X16,
                                                  const _Float16* __restrict__ G16,
                                                  _Float16* __restrict__ T16) {
  __shared__ __align__(16) _Float16 As[128 * 512];
  __shared__ __align__(16) _Float16 Bs[3][128 * 32];
  const int t = threadIdx.x;
  const int lane = t & 63, wave = t >> 6;
  const int wm = (wave >> 2) << 6, wn = (wave & 3) << 5;
  const int lr = lane & 15, lg = lane >> 4;
  const int bn = blockIdx.x << 7;
  const int bm = blockIdx.y << 7;
  const int z = blockIdx.z;
  const int s = z / NSL;
  const int slice = z - s * NSL;
  const int Rs[3] = {45, 240, 750};
  const int R = Rs[s];
  const _Float16* Ap = G16 + ((size_t)s << 18);      // A = G_s (bm rows, band clip)
  const _Float16* Bp = X16 + ((size_t)slice << 18);  // B = X rows
  _Float16* Tout = T16 + ((size_t)z << 18);          // Tout[a][b] = Ys^T

  int klo = bm - R;
  klo = (klo > 0 ? klo : 0) >> 5;
  int khi = bm + 127 + R;
  if (khi > 511) khi = 511;
  khi >>= 5;

  f32x4 acc[4][2];
#pragma unroll
  for (int i = 0; i < 4; ++i)
#pragma unroll
    for (int j = 0; j < 2; ++j) acc[i][j] = (f32x4){0.f, 0.f, 0.f, 0.f};

  K_PIPELINE_LOOP();

  // D[a][b]: a = bm+wm+fm*16+lg*4+j, b = bn+wn+fn*16+lr. Row-major runs.
#pragma unroll
  for (int fm = 0; fm < 4; ++fm)
#pragma unroll
    for (int fn = 0; fn < 2; ++fn) {
      const int a0 = bm + wm + (fm << 4) + (lg << 2);
      const int b0 = bn + wn + (fn << 4) + lr;
#pragma unroll
      for (int j = 0; j < 4; ++j)
        Tout[((size_t)(a0 + j) << 9) + b0] = (_Float16)acc[fm][fn][j];
    }
}

// ---------------- stage 2 fused: out = sum_s log(G_s*Y_s + 1)/3, + min/max ----------------
__global__ __launch_bounds__(512, 2) void gemm2_k(const _Float16* __restrict__ G16,
                                                  const _Float16* __restrict__ T16,
                                                  float* __restrict__ out,
                                                  unsigned* __restrict__ mm) {
  __shared__ __align__(16) _Float16 As[128 * 512];
  __shared__ __align__(16) _Float16 Bs[3][128 * 32];
  const int t = threadIdx.x;
  const int lane = t & 63, wave = t >> 6;
  const int wm = (wave >> 2) << 6, wn = (wave & 3) << 5;
  const int lr = lane & 15, lg = lane >> 4;
  const int bn = blockIdx.x << 7;
  const int bm = blockIdx.y << 7;
  const int slice = blockIdx.z;
  const float w3 = 1.f / 3.f;
  const int Rs[3] = {45, 240, 750};

  f32x4 res[4][2];
#pragma unroll
  for (int i = 0; i < 4; ++i)
#pragma unroll
    for (int j = 0; j < 2; ++j) res[i][j] = (f32x4){0.f, 0.f, 0.f, 0.f};

#pragma unroll 1
  for (int s = 0; s < 3; ++s) {
    const int R = Rs[s];
    const _Float16* Ap = G16 + ((size_t)s << 18);
    const _Float16* Bp = T16 + ((size_t)(s * NSL + slice) << 18);
    int klo = bm - R;
    klo = (klo > 0 ? klo : 0) >> 5;
    int khi = bm + 127 + R;
    if (khi > 511) khi = 511;
    khi >>= 5;

    f32x4 acc[4][2];
#pragma unroll
    for (int i = 0; i < 4; ++i)
#pragma unroll
      for (int j = 0; j < 2; ++j) acc[i][j] = (f32x4){0.f, 0.f, 0.f, 0.f};

    if (s > 0) BARRIER();  // all waves done reading previous A/B before overwrite
    K_PIPELINE_LOOP();

#pragma unroll
    for (int fm = 0; fm < 4; ++fm)
#pragma unroll
      for (int fn = 0; fn < 2; ++fn)
#pragma unroll
        for (int j = 0; j < 4; ++j)
          res[fm][fn][j] += w3 * __logf(acc[fm][fn][j] + 1.f);
  }

  // write out + fused per-channel min/max (wave-reduce + per-wave atomic)
  float mn = 3.4e38f, mx = -3.4e38f;
#pragma unroll
  for (int fm = 0; fm < 4; ++fm)
#pragma unroll
    for (int fn = 0; fn < 2; ++fn) {
      const int rb = bm + wm + (fm << 4) + (lg << 2);
      const int cg = bn + wn + (fn << 4) + lr;
      float* op = out + ((size_t)slice << 18) + ((size_t)rb << 9) + cg;
#pragma unroll
      for (int j = 0; j < 4; ++j) {
        const float v = res[fm][fn][j];
        op[j << 9] = v;
        mn = fminf(mn, v);
        mx = fmaxf(mx, v);
      }
    }
#pragma unroll
  for (int off = 32; off > 0; off >>= 1) {
    mn = fminf(mn, __shfl_xor(mn, off));
    mx = fmaxf(mx, __shfl_xor(mx, off));
  }
  if (lane == 0) {
    const int ch = slice % 3;
    atomicMin(&mm[ch], __float_as_uint(mn));  // values >= 0
    atomicMax(&mm[3 + ch], __float_as_uint(mx));
  }
}

// ---------------- normalize ----------------
__global__ __launch_bounds__(256) void norm_k(float* __restrict__ r,
                                              const unsigned* __restrict__ mm) {
  const int b = blockIdx.x;
  const int slice = b >> 4;
  const int piece = b & 15;
  const int ch = slice % 3;
  const float mn = __uint_as_float(mm[ch]);
  const float mx = __uint_as_float(mm[3 + ch]);
  const float inv = 1.f / (mx - mn);
  float* p = r + ((size_t)slice << 18) + (piece << 14);
  const int t = threadIdx.x;
  for (int q = 0; q < 16; ++q) {
    float4 v = *reinterpret_cast<const float4*>(&p[(q * 256 + t) << 2]);
    v.x = (v.x - mn) * inv;
    v.y = (v.y - mn) * inv;
    v.z = (v.z - mn) * inv;
    v.w = (v.w - mn) * inv;
    *reinterpret_cast<float4*>(&p[(q * 256 + t) << 2]) = v;
  }
}

extern "C" void kernel_launch(void* const* d_in, const int* in_sizes, int n_in,
                              void* d_out, int out_size, void* d_ws, size_t ws_size,
                              hipStream_t stream) {
  const float* img = (const float*)d_in[0];
  float* out = (float*)d_out;
  float* wsf = (float*)d_ws;
  unsigned* mm = (unsigned*)(wsf + MM_OFF);
  _Float16* G16 = (_Float16*)((char*)d_ws + G16_BYTE_OFF);
  _Float16* X16 = (_Float16*)((char*)d_ws + X16_BYTE_OFF);
  _Float16* T16 = (_Float16*)((char*)d_ws + T16_BYTE_OFF);

  wkern<<<3, 256, 0, stream>>>(wsf);
  mm_init<<<1, 64, 0, stream>>>(mm);
  gkern<<<dim3(512, 3), 256, 0, stream>>>(wsf, G16);
  xconv<<<6144, 256, 0, stream>>>(img, X16);

  gemm1_k<<<dim3(4, 4, 3 * NSL), 512, 0, stream>>>(X16, G16, T16);
  gemm2_k<<<dim3(4, 4, NSL), 512, 0, stream>>>(G16, T16, out, mm);

  norm_k<<<768, 256, 0, stream>>>(out, mm);
}

// Round 12
// 217.755 us; speedup vs baseline: 1.4066x; 1.4066x over previous
//
#include <hip/hip_runtime.h>
#include <math.h>

// Retinex MSR via GEMM: blur_s = G_s * X * G_s  (G_s symmetric Toeplitz blur).
// xconv: X -> f16. gemm1 (z=144): Ys^T[a][b] = sum_k G_s[a][k] X[b][k].
// gemm2 (z=48):  out = sum_s log(G_s*Y_s + 1)/3, fused min/max reduction.
// GEMM core: 256x128 tile, BK=64, 8 waves (wave-tile 64x64), 3 LDS buffers,
// 2 interleaved phases per K-tile (ds_read || stage-issue || MFMA cluster with
// setprio), counted vmcnt(6) once per K-tile, XOR-swizzled LDS (pre-swizzled
// global source). norm: min-max stretch.

#define NSL 48

// d_ws layout:
#define W0_OFF 0      // sigma 15:  16 zero | 91 w | zeros   (alloc 512 floats)
#define W1_OFF 512    // sigma 80:  16 zero | 481 w | zeros  (alloc 768)
#define W2_OFF 1280   // sigma 250: 16 zero | 1501 w | zeros (alloc 1536)
#define MM_OFF 2816   // 6 uints: min[3], max[3]
#define G16_BYTE_OFF 16384     // 3 * 512*512 f16   (1.5 MiB)
#define X16_BYTE_OFF 1589248   // 48 * 512*512 f16  (24 MiB)
#define T16_BYTE_OFF 26755072  // 3 * 48 * 512*512 f16 (72 MiB)

typedef _Float16 half8 __attribute__((ext_vector_type(8)));
typedef float f32x4 __attribute__((ext_vector_type(4)));

__device__ __forceinline__ void gload16(const void* g, void* l) {
  __builtin_amdgcn_global_load_lds(
      (const __attribute__((address_space(1))) void*)g,
      (__attribute__((address_space(3))) void*)l, 16, 0, 0);
}

#define WAITV6() asm volatile("s_waitcnt vmcnt(6)" ::: "memory")
#define WAITV0() asm volatile("s_waitcnt vmcnt(0)" ::: "memory")
#define LGKM0() asm volatile("s_waitcnt lgkmcnt(0)" ::: "memory")
#define SCHEDB() __builtin_amdgcn_sched_barrier(0)
#define BARRIER() __builtin_amdgcn_s_barrier()

// ---------------- weights ----------------
__global__ void wkern(float* __restrict__ ws) {
  __shared__ float red[256];
  const int s = blockIdx.x;
  const int Ks[3] = {91, 481, 1501};
  const float sg[3] = {15.f, 80.f, 250.f};
  const int off[3] = {W0_OFF, W1_OFF, W2_OFF};
  const int alloc[3] = {512, 768, 1536};
  const int K = Ks[s], A = alloc[s];
  float* wb = ws + off[s];
  const int t = threadIdx.x;
  for (int i = t; i < A; i += 256) wb[i] = 0.f;
  __syncthreads();
  const float inv2s2 = 1.f / (2.f * sg[s] * sg[s]);
  float part = 0.f;
  for (int i = t; i < K; i += 256) {
    const float d = (float)(i - K / 2);
    const float e = __expf(-d * d * inv2s2);
    wb[16 + i] = e;
    part += e;
  }
  red[t] = part;
  __syncthreads();
  for (int st = 128; st > 0; st >>= 1) {
    if (t < st) red[t] += red[t + st];
    __syncthreads();
  }
  const float inv = 1.f / red[0];
  for (int i = t; i < K; i += 256) wb[16 + i] *= inv;
}

__global__ void mm_init(unsigned* __restrict__ mm) {
  const int t = threadIdx.x;
  if (t < 3) mm[t] = 0xFFFFFFFFu;
  else if (t < 6) mm[t] = 0u;
}

// ---------------- build G matrices (fp16) ----------------
__global__ void gkern(const float* __restrict__ ws, _Float16* __restrict__ gb) {
  const int y = blockIdx.x;
  const int s = blockIdx.y;
  const int Rs[3] = {45, 240, 750};
  const int off[3] = {W0_OFF, W1_OFF, W2_OFF};
  const float* w = ws + off[s] + 16;
  _Float16* g = gb + ((size_t)s << 18) + ((size_t)y << 9);
  const int R = Rs[s], K = 2 * R + 1;
  for (int x = threadIdx.x; x < 512; x += 256) {
    const int i = x - y + R;
    const float v = (i >= 0 && i < K) ? w[i] : 0.f;
    g[x] = (_Float16)v;
  }
}

// ---------------- X fp32 -> fp16 ----------------
__global__ __launch_bounds__(256) void xconv(const float* __restrict__ X,
                                             _Float16* __restrict__ X16) {
  const size_t i = ((size_t)blockIdx.x * 256 + threadIdx.x) << 3;
  const float4 v0 = *reinterpret_cast<const float4*>(X + i);
  const float4 v1 = *reinterpret_cast<const float4*>(X + i + 4);
  half8 h;
  h[0] = (_Float16)v0.x; h[1] = (_Float16)v0.y;
  h[2] = (_Float16)v0.z; h[3] = (_Float16)v0.w;
  h[4] = (_Float16)v1.x; h[5] = (_Float16)v1.y;
  h[6] = (_Float16)v1.z; h[7] = (_Float16)v1.w;
  *reinterpret_cast<half8*>(X16 + i) = h;
}

// ---- staging: A tile 256x64 (4 issues/thread), B tile 128x64 (2 issues).
// LDS granule (row,gc) holds source granule gc^(row&7) (involution); reads
// apply the same XOR. global_load_lds dest stays linear per wave.
#define STG_A(buf, k0, i)                                                        \
  do {                                                                           \
    const int G_ = ((i) << 9) + t;                                               \
    const int r_ = G_ >> 3, g_ = G_ & 7;                                         \
    gload16(Ap + ((size_t)(bm + r_) << 9) + (k0) + ((g_ ^ (r_ & 7)) << 3),       \
            &As[buf][G_ << 3]);                                                  \
  } while (0)

#define STG_B(buf, k0, i)                                                        \
  do {                                                                           \
    const int G_ = ((i) << 9) + t;                                               \
    const int r_ = G_ >> 3, g_ = G_ & 7;                                         \
    gload16(Bp + ((size_t)(bn + r_) << 9) + (k0) + ((g_ ^ (r_ & 7)) << 3),       \
            &Bs[buf][G_ << 3]);                                                  \
  } while (0)

#define STAGE_FULL(buf, k0)                                                      \
  do {                                                                           \
    STG_A(buf, k0, 0); STG_A(buf, k0, 1); STG_A(buf, k0, 2); STG_A(buf, k0, 3);  \
    STG_B(buf, k0, 0); STG_B(buf, k0, 1);                                        \
  } while (0)

// fragment reads for kslot p (swizzled)
#define DSR(buf, p)                                                              \
  do {                                                                           \
    _Pragma("unroll") for (int f = 0; f < 4; ++f) {                              \
      const int rA_ = wm + (f << 4) + lr;                                        \
      af[f] = *reinterpret_cast<const half8*>(                                   \
          &As[buf][(rA_ << 6) + ((((p << 2) + lg) ^ (rA_ & 7)) << 3)]);          \
      const int rB_ = wn + (f << 4) + lr;                                        \
      bf[f] = *reinterpret_cast<const half8*>(                                   \
          &Bs[buf][(rB_ << 6) + ((((p << 2) + lg) ^ (rB_ & 7)) << 3)]);          \
    }                                                                            \
  } while (0)

#define MFMA16()                                                                 \
  _Pragma("unroll") for (int fm = 0; fm < 4; ++fm)                               \
      _Pragma("unroll") for (int fn = 0; fn < 4; ++fn)                           \
      acc[fm][fn] = __builtin_amdgcn_mfma_f32_16x16x32_f16(af[fm], bf[fn],       \
                                                           acc[fm][fn], 0, 0, 0)

// K-loop: 3 buffers mod 3; per K-tile 2 phases; counted vmcnt once per tile.
// Safety: stage of tile t+2 targets buf sb=cb+2 (mod 3), read as tile t-1 and
// fully lgkm-drained before the iter-(t-1) end barrier; each wave vmcnt-drains
// its own tile writes before the shared end barrier (visibility).
#define K_PIPELINE_LOOP()                                                        \
  do {                                                                           \
    BARRIER();                                                                   \
    STAGE_FULL(0, klo << 6);                                                     \
    if (klo + 1 <= khi) {                                                        \
      STAGE_FULL(1, (klo + 1) << 6);                                             \
      WAITV6();                                                                  \
    } else {                                                                     \
      WAITV0();                                                                  \
    }                                                                            \
    SCHEDB();                                                                    \
    BARRIER();                                                                   \
    int cb = 0;                                                                  \
    for (int kt = klo; kt <= khi; ++kt) {                                        \
      const int k2 = (kt + 2) << 6;                                              \
      const bool st = (kt + 2 <= khi);                                           \
      const int sb = (cb + 2 >= 3) ? cb - 1 : cb + 2;                            \
      { /* phase 0 */                                                            \
        half8 af[4], bf[4];                                                      \
        DSR(cb, 0);                                                              \
        if (st) { STG_A(sb, k2, 0); STG_A(sb, k2, 1); STG_A(sb, k2, 2); }        \
        SCHEDB();                                                                \
        BARRIER();                                                               \
        LGKM0();                                                                 \
        SCHEDB();                                                                \
        __builtin_amdgcn_s_setprio(1);                                           \
        MFMA16();                                                                \
        __builtin_amdgcn_s_setprio(0);                                           \
      }                                                                          \
      SCHEDB();                                                                  \
      BARRIER();                                                                 \
      { /* phase 1 */                                                            \
        half8 af[4], bf[4];                                                      \
        DSR(cb, 1);                                                              \
        if (st) { STG_A(sb, k2, 3); STG_B(sb, k2, 0); STG_B(sb, k2, 1); }        \
        SCHEDB();                                                                \
        BARRIER();                                                               \
        LGKM0();                                                                 \
        SCHEDB();                                                                \
        __builtin_amdgcn_s_setprio(1);                                           \
        MFMA16();                                                                \
        __builtin_amdgcn_s_setprio(0);                                           \
      }                                                                          \
      if (kt < khi) {                                                            \
        if (kt + 2 <= khi) { WAITV6(); } else { WAITV0(); }                      \
      }                                                                          \
      SCHEDB();                                                                  \
      BARRIER();                                                                 \
      cb = (cb == 2) ? 0 : cb + 1;                                               \
    }                                                                            \
  } while (0)

// ---------------- stage 1: Ys^T = G_s * X^T (B = X rows), one dispatch all s ----------------
__global__ __launch_bounds__(512, 2) void gemm1_k(const _Float16* __restrict__ X16,
                                                  const _Float16* __restrict__ G16,
                                                  _Float16* __restrict__ T16) {
  __shared__ __align__(16) _Float16 As[3][256 * 64];
  __shared__ __align__(16) _Float16 Bs[3][128 * 64];
  const int t = threadIdx.x;
  const int lane = t & 63, wave = t >> 6;
  const int wm = (wave >> 1) << 6;  // 0,64,128,192
  const int wn = (wave & 1) << 6;   // 0,64
  const int lr = lane & 15, lg = lane >> 4;
  const int bn = blockIdx.x << 7;   // N tile (128)
  const int bm = blockIdx.y << 8;   // M tile (256)
  const int z = blockIdx.z;
  const int s = z / NSL;
  const int slice = z - s * NSL;
  const int Rs[3] = {45, 240, 750};
  const int R = Rs[s];
  const _Float16* Ap = G16 + ((size_t)s << 18);      // A = G_s (bm rows, band clip)
  const _Float16* Bp = X16 + ((size_t)slice << 18);  // B = X rows
  _Float16* Tout = T16 + ((size_t)z << 18);          // Tout[a][b] = Ys^T

  int klo = bm - R;
  klo = (klo > 0 ? klo : 0) >> 6;
  int khi = bm + 255 + R;
  if (khi > 511) khi = 511;
  khi >>= 6;

  f32x4 acc[4][4];
#pragma unroll
  for (int i = 0; i < 4; ++i)
#pragma unroll
    for (int j = 0; j < 4; ++j) acc[i][j] = (f32x4){0.f, 0.f, 0.f, 0.f};

  K_PIPELINE_LOOP();

  // D[a][b]: a = bm+wm+fm*16+lg*4+j, b = bn+wn+fn*16+lr. Row-major runs.
#pragma unroll
  for (int fm = 0; fm < 4; ++fm)
#pragma unroll
    for (int fn = 0; fn < 4; ++fn) {
      const int a0 = bm + wm + (fm << 4) + (lg << 2);
      const int b0 = bn + wn + (fn << 4) + lr;
#pragma unroll
      for (int j = 0; j < 4; ++j)
        Tout[((size_t)(a0 + j) << 9) + b0] = (_Float16)acc[fm][fn][j];
    }
}

// ---------------- stage 2 fused: out = sum_s log(G_s*Y_s + 1)/3, + min/max ----------------
__global__ __launch_bounds__(512, 2) void gemm2_k(const _Float16* __restrict__ G16,
                                                  const _Float16* __restrict__ T16,
                                                  float* __restrict__ out,
                                                  unsigned* __restrict__ mm) {
  __shared__ __align__(16) _Float16 As[3][256 * 64];
  __shared__ __align__(16) _Float16 Bs[3][128 * 64];
  const int t = threadIdx.x;
  const int lane = t & 63, wave = t >> 6;
  const int wm = (wave >> 1) << 6;
  const int wn = (wave & 1) << 6;
  const int lr = lane & 15, lg = lane >> 4;
  const int bn = blockIdx.x << 7;
  const int bm = blockIdx.y << 8;
  const int slice = blockIdx.z;
  const float w3 = 1.f / 3.f;
  const int Rs[3] = {45, 240, 750};

  f32x4 res[4][4];
#pragma unroll
  for (int i = 0; i < 4; ++i)
#pragma unroll
    for (int j = 0; j < 4; ++j) res[i][j] = (f32x4){0.f, 0.f, 0.f, 0.f};

#pragma unroll 1
  for (int s = 0; s < 3; ++s) {
    const int R = Rs[s];
    const _Float16* Ap = G16 + ((size_t)s << 18);
    const _Float16* Bp = T16 + ((size_t)(s * NSL + slice) << 18);
    int klo = bm - R;
    klo = (klo > 0 ? klo : 0) >> 6;
    int khi = bm + 255 + R;
    if (khi > 511) khi = 511;
    khi >>= 6;

    f32x4 acc[4][4];
#pragma unroll
    for (int i = 0; i < 4; ++i)
#pragma unroll
      for (int j = 0; j < 4; ++j) acc[i][j] = (f32x4){0.f, 0.f, 0.f, 0.f};

    K_PIPELINE_LOOP();

#pragma unroll
    for (int fm = 0; fm < 4; ++fm)
#pragma unroll
      for (int fn = 0; fn < 4; ++fn)
#pragma unroll
        for (int j = 0; j < 4; ++j)
          res[fm][fn][j] += w3 * __logf(acc[fm][fn][j] + 1.f);
  }

  // write out + fused per-channel min/max (wave-reduce + per-wave atomic)
  float mn = 3.4e38f, mx = -3.4e38f;
#pragma unroll
  for (int fm = 0; fm < 4; ++fm)
#pragma unroll
    for (int fn = 0; fn < 4; ++fn) {
      const int rb = bm + wm + (fm << 4) + (lg << 2);
      const int cg = bn + wn + (fn << 4) + lr;
      float* op = out + ((size_t)slice << 18) + ((size_t)rb << 9) + cg;
#pragma unroll
      for (int j = 0; j < 4; ++j) {
        const float v = res[fm][fn][j];
        op[j << 9] = v;
        mn = fminf(mn, v);
        mx = fmaxf(mx, v);
      }
    }
#pragma unroll
  for (int off = 32; off > 0; off >>= 1) {
    mn = fminf(mn, __shfl_xor(mn, off));
    mx = fmaxf(mx, __shfl_xor(mx, off));
  }
  if (lane == 0) {
    const int ch = slice % 3;
    atomicMin(&mm[ch], __float_as_uint(mn));  // values >= 0
    atomicMax(&mm[3 + ch], __float_as_uint(mx));
  }
}

// ---------------- normalize ----------------
__global__ __launch_bounds__(256) void norm_k(float* __restrict__ r,
                                              const unsigned* __restrict__ mm) {
  const int b = blockIdx.x;
  const int slice = b >> 4;
  const int piece = b & 15;
  const int ch = slice % 3;
  const float mn = __uint_as_float(mm[ch]);
  const float mx = __uint_as_float(mm[3 + ch]);
  const float inv = 1.f / (mx - mn);
  float* p = r + ((size_t)slice << 18) + (piece << 14);
  const int t = threadIdx.x;
  for (int q = 0; q < 16; ++q) {
    float4 v = *reinterpret_cast<const float4*>(&p[(q * 256 + t) << 2]);
    v.x = (v.x - mn) * inv;
    v.y = (v.y - mn) * inv;
    v.z = (v.z - mn) * inv;
    v.w = (v.w - mn) * inv;
    *reinterpret_cast<float4*>(&p[(q * 256 + t) << 2]) = v;
  }
}

extern "C" void kernel_launch(void* const* d_in, const int* in_sizes, int n_in,
                              void* d_out, int out_size, void* d_ws, size_t ws_size,
                              hipStream_t stream) {
  const float* img = (const float*)d_in[0];
  float* out = (float*)d_out;
  float* wsf = (float*)d_ws;
  unsigned* mm = (unsigned*)(wsf + MM_OFF);
  _Float16* G16 = (_Float16*)((char*)d_ws + G16_BYTE_OFF);
  _Float16* X16 = (_Float16*)((char*)d_ws + X16_BYTE_OFF);
  _Float16* T16 = (_Float16*)((char*)d_ws + T16_BYTE_OFF);

  wkern<<<3, 256, 0, stream>>>(wsf);
  mm_init<<<1, 64, 0, stream>>>(mm);
  gkern<<<dim3(512, 3), 256, 0, stream>>>(wsf, G16);
  xconv<<<6144, 256, 0, stream>>>(img, X16);

  gemm1_k<<<dim3(4, 2, 3 * NSL), 512, 0, stream>>>(X16, G16, T16);
  gemm2_k<<<dim3(4, 2, NSL), 512, 0, stream>>>(G16, T16, out, mm);

  norm_k<<<768, 256, 0, stream>>>(out, mm);
}

// Round 13
// 177.025 us; speedup vs baseline: 1.7303x; 1.2301x over previous
//
#include <hip/hip_runtime.h>
#include <math.h>

// Retinex MSR via GEMM: blur_s = G_s * X * G_s  (G_s symmetric Toeplitz blur).
// xconv: X -> f16. gemm1: Ys^T[a][b] = sum_k G_s[a][k] X[b][k].
// gemm2: out = sum_s log(G_s*Y_s + 1)/3, fused min/max reduction.
// GEMM core = round-8 structure (best measured): 128x128 tile, BK=32, 3 LDS
// buffers, counted vmcnt(4) + raw s_barrier per K-step, pointer staging.
// NEW (launcher only): slice-batched g1/g2 interleave (2 batches x 24 slices)
// so T16 per batch (36MB) is read while still L3-resident after being written.

#define NSL 48
#define SLB 24  // slices per batch

// d_ws layout:
#define W0_OFF 0      // sigma 15:  16 zero | 91 w | zeros   (alloc 512 floats)
#define W1_OFF 512    // sigma 80:  16 zero | 481 w | zeros  (alloc 768)
#define W2_OFF 1280   // sigma 250: 16 zero | 1501 w | zeros (alloc 1536)
#define MM_OFF 2816   // 6 uints: min[3], max[3]
#define G16_BYTE_OFF 16384     // 3 * 512*512 f16   (1.5 MiB)
#define X16_BYTE_OFF 1589248   // 48 * 512*512 f16  (24 MiB)
#define T16_BYTE_OFF 26755072  // 3 * 48 * 512*512 f16 (72 MiB)

typedef _Float16 half8 __attribute__((ext_vector_type(8)));
typedef float f32x4 __attribute__((ext_vector_type(4)));

__device__ __forceinline__ void gload16(const void* g, void* l) {
  __builtin_amdgcn_global_load_lds(
      (const __attribute__((address_space(1))) void*)g,
      (__attribute__((address_space(3))) void*)l, 16, 0, 0);
}

#define WAITV4() asm volatile("s_waitcnt vmcnt(4)" ::: "memory")
#define WAITV0() asm volatile("s_waitcnt vmcnt(0)" ::: "memory")
#define SCHEDB() __builtin_amdgcn_sched_barrier(0)
#define BARRIER() __builtin_amdgcn_s_barrier()

// ---------------- weights ----------------
__global__ void wkern(float* __restrict__ ws) {
  __shared__ float red[256];
  const int s = blockIdx.x;
  const int Ks[3] = {91, 481, 1501};
  const float sg[3] = {15.f, 80.f, 250.f};
  const int off[3] = {W0_OFF, W1_OFF, W2_OFF};
  const int alloc[3] = {512, 768, 1536};
  const int K = Ks[s], A = alloc[s];
  float* wb = ws + off[s];
  const int t = threadIdx.x;
  for (int i = t; i < A; i += 256) wb[i] = 0.f;
  __syncthreads();
  const float inv2s2 = 1.f / (2.f * sg[s] * sg[s]);
  float part = 0.f;
  for (int i = t; i < K; i += 256) {
    const float d = (float)(i - K / 2);
    const float e = __expf(-d * d * inv2s2);
    wb[16 + i] = e;
    part += e;
  }
  red[t] = part;
  __syncthreads();
  for (int st = 128; st > 0; st >>= 1) {
    if (t < st) red[t] += red[t + st];
    __syncthreads();
  }
  const float inv = 1.f / red[0];
  for (int i = t; i < K; i += 256) wb[16 + i] *= inv;
}

__global__ void mm_init(unsigned* __restrict__ mm) {
  const int t = threadIdx.x;
  if (t < 3) mm[t] = 0xFFFFFFFFu;
  else if (t < 6) mm[t] = 0u;
}

// ---------------- build G matrices (fp16) ----------------
__global__ void gkern(const float* __restrict__ ws, _Float16* __restrict__ gb) {
  const int y = blockIdx.x;
  const int s = blockIdx.y;
  const int Rs[3] = {45, 240, 750};
  const int off[3] = {W0_OFF, W1_OFF, W2_OFF};
  const float* w = ws + off[s] + 16;
  _Float16* g = gb + ((size_t)s << 18) + ((size_t)y << 9);
  const int R = Rs[s], K = 2 * R + 1;
  for (int x = threadIdx.x; x < 512; x += 256) {
    const int i = x - y + R;
    const float v = (i >= 0 && i < K) ? w[i] : 0.f;
    g[x] = (_Float16)v;
  }
}

// ---------------- X fp32 -> fp16 ----------------
__global__ __launch_bounds__(256) void xconv(const float* __restrict__ X,
                                             _Float16* __restrict__ X16) {
  const size_t i = ((size_t)blockIdx.x * 256 + threadIdx.x) << 3;
  const float4 v0 = *reinterpret_cast<const float4*>(X + i);
  const float4 v1 = *reinterpret_cast<const float4*>(X + i + 4);
  half8 h;
  h[0] = (_Float16)v0.x; h[1] = (_Float16)v0.y;
  h[2] = (_Float16)v0.z; h[3] = (_Float16)v0.w;
  h[4] = (_Float16)v1.x; h[5] = (_Float16)v1.y;
  h[6] = (_Float16)v1.z; h[7] = (_Float16)v1.w;
  *reinterpret_cast<half8*>(X16 + i) = h;
}

// stage via pre-computed per-thread pointers; advance by BK (32 elems) after.
#define STAGE_P(buf)                                 \
  do {                                               \
    gload16(pA0, &As[buf][t << 3]);                  \
    gload16(pA1, &As[buf][(256 + t) << 3]);          \
    gload16(pB0, &Bs[buf][t << 3]);                  \
    gload16(pB1, &Bs[buf][(256 + t) << 3]);          \
    pA0 += 32; pA1 += 32; pB0 += 32; pB1 += 32;      \
  } while (0)

#define FRAGS_AND_MFMA(buf)                                                         \
  do {                                                                              \
    half8 af[4], bf[4];                                                             \
    _Pragma("unroll") for (int f = 0; f < 4; ++f) {                                 \
      af[f] = *reinterpret_cast<const half8*>(                                      \
          &As[buf][(((wr << 6) + (f << 4) + lr) << 5) + (lg << 3)]);                \
      bf[f] = *reinterpret_cast<const half8*>(                                      \
          &Bs[buf][(((wc << 6) + (f << 4) + lr) << 5) + (lg << 3)]);                \
    }                                                                               \
    _Pragma("unroll") for (int fm = 0; fm < 4; ++fm)                                \
        _Pragma("unroll") for (int fn = 0; fn < 4; ++fn)                            \
        acc[fm][fn] = __builtin_amdgcn_mfma_f32_16x16x32_f16(af[fm], bf[fn],        \
                                                             acc[fm][fn], 0, 0, 0); \
  } while (0)

// Pipelined K-loop: buffers cycle mod 3; one raw barrier + counted vmcnt per step.
#define K_PIPELINE_LOOP()                                                           \
  do {                                                                              \
    const int row_ = t >> 2;                                                        \
    const int c8_ = (t & 3) << 3;                                                   \
    const _Float16* pA0 =                                                           \
        Ap + ((size_t)(bm + row_) << 9) + (klo << 5) + c8_;                         \
    const _Float16* pA1 = pA0 + ((size_t)64 << 9);                                  \
    const _Float16* pB0 =                                                           \
        Bp + ((size_t)(bn + row_) << 9) + (klo << 5) + c8_;                         \
    const _Float16* pB1 = pB0 + ((size_t)64 << 9);                                  \
    STAGE_P(0);                                                                     \
    STAGE_P(1);                                                                     \
    int cb = 0;                                                                     \
    for (int kt = klo; kt <= khi; ++kt) {                                           \
      if (kt < khi) { WAITV4(); } else { WAITV0(); }                                \
      SCHEDB();                                                                     \
      BARRIER();                                                                    \
      SCHEDB();                                                                     \
      if (kt + 2 <= khi) {                                                          \
        const int sb = (cb + 2 >= 3) ? cb - 1 : cb + 2;                             \
        STAGE_P(sb);                                                                \
      }                                                                             \
      FRAGS_AND_MFMA(cb);                                                           \
      cb = (cb == 2) ? 0 : cb + 1;                                                  \
    }                                                                               \
  } while (0)

// ---------------- stage 1: Ys^T for a 24-slice batch (z = 3*slice_local + s) ----------------
__global__ __launch_bounds__(256) void gemm1_k(const _Float16* __restrict__ X16,
                                               const _Float16* __restrict__ G16,
                                               _Float16* __restrict__ T16,
                                               int base) {
  __shared__ __align__(16) _Float16 As[3][128 * 32];
  __shared__ __align__(16) _Float16 Bs[3][128 * 32];
  const int t = threadIdx.x;
  const int lane = t & 63, wave = t >> 6;
  const int wr = wave >> 1, wc = wave & 1;
  const int lr = lane & 15, lg = lane >> 4;
  const int bn = blockIdx.x << 7;
  const int bm = blockIdx.y << 7;
  const int z = blockIdx.z;
  const int s = z % 3;                         // 3 sigmas of one slice adjacent
  const int slice = base + z / 3;
  const int Rs[3] = {45, 240, 750};
  const int R = Rs[s];
  const _Float16* Ap = G16 + ((size_t)s << 18);      // A = G_s (bm rows, band clip)
  const _Float16* Bp = X16 + ((size_t)slice << 18);  // B = X rows
  _Float16* Tout = T16 + ((size_t)(s * NSL + slice) << 18);  // Tout[a][b] = Ys^T

  int klo = bm - R;
  klo = (klo > 0 ? klo : 0) >> 5;
  int khi = bm + 127 + R;
  if (khi > 511) khi = 511;
  khi >>= 5;

  f32x4 acc[4][4];
#pragma unroll
  for (int i = 0; i < 4; ++i)
#pragma unroll
    for (int j = 0; j < 4; ++j) acc[i][j] = (f32x4){0.f, 0.f, 0.f, 0.f};

  K_PIPELINE_LOOP();

  // D[a][b]: a = bm+wr*64+fm*16+lg*4+j, b = bn+wc*64+fn*16+lr. Row-major runs.
#pragma unroll
  for (int fm = 0; fm < 4; ++fm)
#pragma unroll
    for (int fn = 0; fn < 4; ++fn) {
      const int a0 = bm + (wr << 6) + (fm << 4) + (lg << 2);
      const int b0 = bn + (wc << 6) + (fn << 4) + lr;
#pragma unroll
      for (int j = 0; j < 4; ++j)
        Tout[((size_t)(a0 + j) << 9) + b0] = (_Float16)acc[fm][fn][j];
    }
}

// ---------------- stage 2 fused: out = sum_s log(G_s*Y_s + 1)/3, + min/max ----------------
__global__ __launch_bounds__(256) void gemm2_k(const _Float16* __restrict__ G16,
                                               const _Float16* __restrict__ T16,
                                               float* __restrict__ out,
                                               unsigned* __restrict__ mm,
                                               int base) {
  __shared__ __align__(16) _Float16 As[3][128 * 32];
  __shared__ __align__(16) _Float16 Bs[3][128 * 32];
  __shared__ float smn[4], smx[4];
  const int t = threadIdx.x;
  const int lane = t & 63, wave = t >> 6;
  const int wr = wave >> 1, wc = wave & 1;
  const int lr = lane & 15, lg = lane >> 4;
  const int bn = blockIdx.x << 7;
  const int bm = blockIdx.y << 7;
  const int slice = base + blockIdx.z;
  const float w3 = 1.f / 3.f;
  const int Rs[3] = {45, 240, 750};

  f32x4 res[4][4];
#pragma unroll
  for (int i = 0; i < 4; ++i)
#pragma unroll
    for (int j = 0; j < 4; ++j) res[i][j] = (f32x4){0.f, 0.f, 0.f, 0.f};

  int cur = 0;
#pragma unroll 1
  for (int s = 0; s < 3; ++s) {
    const int R = Rs[s];
    const _Float16* Ap = G16 + ((size_t)s << 18);
    const _Float16* Bp = T16 + ((size_t)(s * NSL + slice) << 18);
    int klo = bm - R;
    klo = (klo > 0 ? klo : 0) >> 5;
    int khi = bm + 127 + R;
    if (khi > 511) khi = 511;
    khi >>= 5;

    f32x4 acc[4][4];
#pragma unroll
    for (int i = 0; i < 4; ++i)
#pragma unroll
      for (int j = 0; j < 4; ++j) acc[i][j] = (f32x4){0.f, 0.f, 0.f, 0.f};

    BARRIER();  // protect buffers 0/1 from previous sigma's late readers
    K_PIPELINE_LOOP();

#pragma unroll
    for (int fm = 0; fm < 4; ++fm)
#pragma unroll
      for (int fn = 0; fn < 4; ++fn)
#pragma unroll
        for (int j = 0; j < 4; ++j)
          res[fm][fn][j] += w3 * __logf(acc[fm][fn][j] + 1.f);
    (void)cur;
  }

  // write out + fused per-channel min/max
  float mn = 3.4e38f, mx = -3.4e38f;
#pragma unroll
  for (int fm = 0; fm < 4; ++fm)
#pragma unroll
    for (int fn = 0; fn < 4; ++fn) {
      const int rb = bm + (wr << 6) + (fm << 4) + (lg << 2);
      const int cg = bn + (wc << 6) + (fn << 4) + lr;
      float* op = out + ((size_t)slice << 18) + ((size_t)rb << 9) + cg;
#pragma unroll
      for (int j = 0; j < 4; ++j) {
        const float v = res[fm][fn][j];
        op[j << 9] = v;
        mn = fminf(mn, v);
        mx = fmaxf(mx, v);
      }
    }
#pragma unroll
  for (int off = 32; off > 0; off >>= 1) {
    mn = fminf(mn, __shfl_xor(mn, off));
    mx = fmaxf(mx, __shfl_xor(mx, off));
  }
  if (lane == 0) {
    smn[wave] = mn;
    smx[wave] = mx;
  }
  __syncthreads();
  if (t == 0) {
    mn = fminf(fminf(smn[0], smn[1]), fminf(smn[2], smn[3]));
    mx = fmaxf(fmaxf(smx[0], smx[1]), fmaxf(smx[2], smx[3]));
    const int ch = slice % 3;
    atomicMin(&mm[ch], __float_as_uint(mn));  // values >= 0
    atomicMax(&mm[3 + ch], __float_as_uint(mx));
  }
}

// ---------------- normalize ----------------
__global__ __launch_bounds__(256) void norm_k(float* __restrict__ r,
                                              const unsigned* __restrict__ mm) {
  const int b = blockIdx.x;
  const int slice = b >> 4;
  const int piece = b & 15;
  const int ch = slice % 3;
  const float mn = __uint_as_float(mm[ch]);
  const float mx = __uint_as_float(mm[3 + ch]);
  const float inv = 1.f / (mx - mn);
  float* p = r + ((size_t)slice << 18) + (piece << 14);
  const int t = threadIdx.x;
  for (int q = 0; q < 16; ++q) {
    float4 v = *reinterpret_cast<const float4*>(&p[(q * 256 + t) << 2]);
    v.x = (v.x - mn) * inv;
    v.y = (v.y - mn) * inv;
    v.z = (v.z - mn) * inv;
    v.w = (v.w - mn) * inv;
    *reinterpret_cast<float4*>(&p[(q * 256 + t) << 2]) = v;
  }
}

extern "C" void kernel_launch(void* const* d_in, const int* in_sizes, int n_in,
                              void* d_out, int out_size, void* d_ws, size_t ws_size,
                              hipStream_t stream) {
  const float* img = (const float*)d_in[0];
  float* out = (float*)d_out;
  float* wsf = (float*)d_ws;
  unsigned* mm = (unsigned*)(wsf + MM_OFF);
  _Float16* G16 = (_Float16*)((char*)d_ws + G16_BYTE_OFF);
  _Float16* X16 = (_Float16*)((char*)d_ws + X16_BYTE_OFF);
  _Float16* T16 = (_Float16*)((char*)d_ws + T16_BYTE_OFF);

  wkern<<<3, 256, 0, stream>>>(wsf);
  mm_init<<<1, 64, 0, stream>>>(mm);
  gkern<<<dim3(512, 3), 256, 0, stream>>>(wsf, G16);
  xconv<<<6144, 256, 0, stream>>>(img, X16);

  for (int b = 0; b < NSL / SLB; ++b) {
    gemm1_k<<<dim3(4, 4, 3 * SLB), 256, 0, stream>>>(X16, G16, T16, b * SLB);
    gemm2_k<<<dim3(4, 4, SLB), 256, 0, stream>>>(G16, T16, out, mm, b * SLB);
  }

  norm_k<<<768, 256, 0, stream>>>(out, mm);
}